// Round 7
// baseline (1628.580 us; speedup 1.0000x reference)
//
#include <hip/hip_runtime.h>
#include <stdint.h>

// Problem: B=64, T=128, F=1024, H=1024. x:[64,128,1024] f32, W:[2048,4096] f32, b:[4096] f32.
// out:[64,128,1024] f32.
#define BATCH 64
#define TSEQ  128
#define FDIM  1024
#define HDIM  1024
#define GDIM  4096              // 4H
#define MROWS 8192              // BATCH*TSEQ
#define NB    128               // persistent blocks in recurrent phase (co-resident on 256 CUs)

typedef short bf16x8 __attribute__((ext_vector_type(8)));   // 8 bf16 in 4 VGPRs
typedef float f32x4  __attribute__((ext_vector_type(4)));

__device__ __forceinline__ unsigned short f2bf(float f) {
    union { float f; uint32_t u; } v; v.f = f;
    uint32_t u = v.u;
    return (unsigned short)((u + 0x7FFFu + ((u >> 16) & 1u)) >> 16);  // RNE
}
__device__ __forceinline__ float bf2f(unsigned short h) {
    union { uint32_t u; float f; } v; v.u = ((uint32_t)h) << 16; return v.f;
}
__device__ __forceinline__ float sigmoidf_(float x) { return 1.f / (1.f + __expf(-x)); }
__device__ __forceinline__ float tanhf_(float x)    { return 2.f / (1.f + __expf(-2.f * x)) - 1.f; }

union SP { short s[8]; int4 v; };
union UU { int4 i; bf16x8 v; };

// L2-bypass 8B store (relaxed agent atomic -> lands at Infinity Cache, the coherent point).
__device__ __forceinline__ void st64cc(void* p, unsigned long long v) {
    __hip_atomic_store((unsigned long long*)p, v, __ATOMIC_RELAXED, __HIP_MEMORY_SCOPE_AGENT);
}
__device__ __forceinline__ f32x4 sx4(f32x4 v, int m) {
    f32x4 r;
    r[0] = __shfl_xor(v[0], m); r[1] = __shfl_xor(v[1], m);
    r[2] = __shfl_xor(v[2], m); r[3] = __shfl_xor(v[3], m);
    return r;
}

// ---------------- init: zero cnt + h slot 0 ----------------
__global__ void k_init(uint32_t* p, int nwords) {
    int i = blockIdx.x * blockDim.x + threadIdx.x;
    int s = gridDim.x * blockDim.x;
    for (; i < nwords; i += s) p[i] = 0;
}

// ---------------- W fp32 [2048][4096] -> WxT hi/lo bf16 [4096][1024], WhT bf16 [4096][1024] ----
__global__ void k_tw(const float* __restrict__ W,
                     unsigned short* __restrict__ wxth, unsigned short* __restrict__ wxtl,
                     unsigned short* __restrict__ wht) {
    __shared__ float tile[64 * 65];
    const int nb = blockIdx.x;      // 0..63  (n tiles)
    const int kb = blockIdx.y;      // 0..31  (k tiles over 2048)
    const int t  = threadIdx.x;
    const int col = t & 63, rg = t >> 6;
#pragma unroll
    for (int i = 0; i < 16; i++) {
        int row = rg * 16 + i;
        tile[row * 65 + col] = W[(size_t)(kb * 64 + row) * 4096 + nb * 64 + col];
    }
    __syncthreads();
    if (kb < 16) {
        const int kbase = kb * 64;
#pragma unroll
        for (int i = 0; i < 16; i++) {
            int rp = rg * 16 + i;                      // n index within tile
            float v = tile[col * 65 + rp];             // = W[kb*64+col][nb*64+rp]
            unsigned short h = f2bf(v);
            size_t idx = (size_t)(nb * 64 + rp) * 1024 + kbase + col;
            wxth[idx] = h;
            wxtl[idx] = f2bf(v - bf2f(h));
        }
    } else {
        const int kbase = (kb - 16) * 64;
#pragma unroll
        for (int i = 0; i < 16; i++) {
            int rp = rg * 16 + i;
            float v = tile[col * 65 + rp];
            wht[(size_t)(nb * 64 + rp) * 1024 + kbase + col] = f2bf(v);
        }
    }
}

// ---------------- GEMM1: xz_f32[8192][4096] = x[8192][1024] @ Wx, split-bf16 (3-MFMA) ---------
__global__ __launch_bounds__(256) void k_gemm1(const float* __restrict__ Xf,
                                               const unsigned short* __restrict__ WxTh,
                                               const unsigned short* __restrict__ WxTl,
                                               float* __restrict__ xz) {
    __shared__ short Ash[128 * 40];   // stride 40 elems (80B) -> 2-way banks (free)
    __shared__ short Asl[128 * 40];
    __shared__ short Bsh[128 * 40];
    __shared__ short Bsl[128 * 40];
    const int n0 = blockIdx.x * 128;
    const int m0 = blockIdx.y * 128;
    const int t = threadIdx.x;
    const int wave = t >> 6, lane = t & 63;
    const int wm = wave >> 1, wn = wave & 1;
    const int q = lane >> 4, cl = lane & 15;
    const int row_a = t >> 2;            // 0..63
    const int kc = (t & 3) * 8;          // 8-elem chunk within the 32-elem k-slab

    f32x4 acc[4][4];
#pragma unroll
    for (int i = 0; i < 4; i++)
#pragma unroll
        for (int j = 0; j < 4; j++) acc[i][j] = (f32x4){0.f, 0.f, 0.f, 0.f};

    for (int kb = 0; kb < 32; kb++) {
        const int k0 = kb * 32;
        float va0[8], va1[8];
        {
            const float* p0 = Xf + (size_t)(m0 + row_a) * 1024 + k0 + kc;
            const float* p1 = Xf + (size_t)(m0 + 64 + row_a) * 1024 + k0 + kc;
            *(float4*)(va0)     = *(const float4*)(p0);
            *(float4*)(va0 + 4) = *(const float4*)(p0 + 4);
            *(float4*)(va1)     = *(const float4*)(p1);
            *(float4*)(va1 + 4) = *(const float4*)(p1 + 4);
        }
        int4 bh0 = *(const int4*)(WxTh + (size_t)(n0 + row_a)      * 1024 + k0 + kc);
        int4 bh1 = *(const int4*)(WxTh + (size_t)(n0 + 64 + row_a) * 1024 + k0 + kc);
        int4 bl0 = *(const int4*)(WxTl + (size_t)(n0 + row_a)      * 1024 + k0 + kc);
        int4 bl1 = *(const int4*)(WxTl + (size_t)(n0 + 64 + row_a) * 1024 + k0 + kc);
        __syncthreads();
        {
            SP h0, l0, h1, l1;
#pragma unroll
            for (int i = 0; i < 8; i++) {
                unsigned short h = f2bf(va0[i]);
                h0.s[i] = (short)h; l0.s[i] = (short)f2bf(va0[i] - bf2f(h));
                unsigned short g = f2bf(va1[i]);
                h1.s[i] = (short)g; l1.s[i] = (short)f2bf(va1[i] - bf2f(g));
            }
            *(int4*)(Ash + row_a * 40 + kc)        = h0.v;
            *(int4*)(Asl + row_a * 40 + kc)        = l0.v;
            *(int4*)(Ash + (64 + row_a) * 40 + kc) = h1.v;
            *(int4*)(Asl + (64 + row_a) * 40 + kc) = l1.v;
        }
        *(int4*)(Bsh + row_a * 40 + kc)        = bh0;
        *(int4*)(Bsh + (64 + row_a) * 40 + kc) = bh1;
        *(int4*)(Bsl + row_a * 40 + kc)        = bl0;
        *(int4*)(Bsl + (64 + row_a) * 40 + kc) = bl1;
        __syncthreads();
        bf16x8 ah[4], al[4], bh[4], bl[4];
#pragma unroll
        for (int i = 0; i < 4; i++) {
            ah[i] = *(const bf16x8*)(Ash + (wm * 64 + i * 16 + cl) * 40 + q * 8);
            al[i] = *(const bf16x8*)(Asl + (wm * 64 + i * 16 + cl) * 40 + q * 8);
        }
#pragma unroll
        for (int j = 0; j < 4; j++) {
            bh[j] = *(const bf16x8*)(Bsh + (wn * 64 + j * 16 + cl) * 40 + q * 8);
            bl[j] = *(const bf16x8*)(Bsl + (wn * 64 + j * 16 + cl) * 40 + q * 8);
        }
#pragma unroll
        for (int i = 0; i < 4; i++)
#pragma unroll
            for (int j = 0; j < 4; j++) {
                acc[i][j] = __builtin_amdgcn_mfma_f32_16x16x32_bf16(ah[i], bh[j], acc[i][j], 0, 0, 0);
                acc[i][j] = __builtin_amdgcn_mfma_f32_16x16x32_bf16(al[i], bh[j], acc[i][j], 0, 0, 0);
                acc[i][j] = __builtin_amdgcn_mfma_f32_16x16x32_bf16(ah[i], bl[j], acc[i][j], 0, 0, 0);
            }
    }
    // epilogue: C/D layout col=lane&15, row=q*4+reg; write fp32
#pragma unroll
    for (int i = 0; i < 4; i++) {
#pragma unroll
        for (int j = 0; j < 4; j++) {
            int gm = m0 + wm * 64 + i * 16 + q * 4;
            int gn = n0 + wn * 64 + j * 16 + cl;
#pragma unroll
            for (int r = 0; r < 4; r++)
                xz[(size_t)(gm + r) * 4096 + gn] = acc[i][j][r];
        }
    }
}

// ---------------- persistent recurrent kernel (R7: Wh in REGISTERS) ----------------
// NB=128 blocks x 256 thr. Block owns 8 h-cols -> 32 gate cols [i(8) j(8) | f(8) o(8)].
// Waves: (rowhalf rh, khalf kh). Each wave: 32 rows x 32 cols x 512 k; its B-fragments
// (2 n-tiles x 16 ksteps = 128 VGPRs) are loaded from WhT ONCE and held for all 128 steps
// -> zero LDS traffic in the MFMA loop (R6's 256 ds_read_b128/step was the bottleneck).
// k-split pairs reduced via 18KB LDS; gate regroup via shfl_xor{2,4,6}; h stored as 8B
// sc-stores into the rotating write-once buffer; consumers use cached 16B loads (L2-shared/XCD).
__global__ __launch_bounds__(256, 1) void k_rnn(const float* __restrict__ xz,
                                                const unsigned short* __restrict__ WhT,
                                                const float* __restrict__ bias,
                                                unsigned short* hrot,    // 129 x [64][1024] bf16
                                                int* cnt,                // TSEQ step counters
                                                float* __restrict__ out) {
    __shared__ float Lp[2 * 64 * 36];   // [kh][row 64][col 32 + pad 4] = 18 KB
    const int t = threadIdx.x;
    const int blk = blockIdx.x;
    // XCD-grouped columns: blocks with blk&7==x own cols [x*128, x*128+128)
    const int n0 = (((blk & 7) << 4) | (blk >> 3)) * 8;
    const int wave = t >> 6, lane = t & 63;
    const int q = lane >> 4, cl = lane & 15;
    const int rh = wave >> 1, kh = wave & 1;

    // ---- B (Wh) preload into registers: br[n][s] = B[col=n*16+cl][k=kh*512+s*32+q*8 ..+8]
    bf16x8 br[2][16];
#pragma unroll
    for (int n = 0; n < 2; n++) {
        const int vcol = n * 16 + cl;
        const int gg = vcol >> 3, cc = vcol & 7;
        const unsigned short* wrow = WhT + (size_t)(gg * 1024 + n0 + cc) * 1024 + kh * 512 + q * 8;
#pragma unroll
        for (int s = 0; s < 16; s++) {
            UU u; u.i = *(const int4*)(wrow + s * 32);
            br[n][s] = u.v;
        }
    }

    // ---- reducer / gate role: thread t -> rows {r0, r0+32}, col-quad `quad` (4 cols)
    const int quad = t & 7;             // 0..7: gate g = quad>>1, col-half ch = quad&1
    const int r0 = t >> 3;              // 0..31
    const int g = quad >> 1, ch = quad & 1;
    const f32x4 bv = *(const f32x4*)(bias + g * 1024 + n0 + ch * 4);
    float cst[2][4] = {{0.f, 0.f, 0.f, 0.f}, {0.f, 0.f, 0.f, 0.f}};

    for (int tt = 0; tt < TSEQ; tt++) {
        // xz prefetch for own gate slice (16B loads), issued before the spin
        f32x4 px0, px1;
        {
            const float* xp = xz + (size_t)(r0 * 128 + tt) * 4096 + g * 1024 + n0 + ch * 4;
            px0 = *(const f32x4*)xp;
            px1 = *(const f32x4*)(xp + (size_t)32 * 128 * 4096);
        }
        if (tt > 0) {
            if (t == 0) {
                while (__hip_atomic_load(&cnt[tt - 1], __ATOMIC_RELAXED,
                                         __HIP_MEMORY_SCOPE_AGENT) < NB) { }
            }
            __syncthreads();
        }
        // ---- MFMA: A from rotating h slot (cached loads), B from registers
        f32x4 a00 = (f32x4){0.f,0.f,0.f,0.f}, a01 = (f32x4){0.f,0.f,0.f,0.f};
        f32x4 a10 = (f32x4){0.f,0.f,0.f,0.f}, a11 = (f32x4){0.f,0.f,0.f,0.f};
        const char* slot = (const char*)hrot + (size_t)tt * 131072;
        const char* pa0 = slot + (size_t)(rh * 32 + cl) * 2048 + kh * 1024 + q * 16;
        const char* pa1 = pa0 + 16 * 2048;
#pragma unroll
        for (int s = 0; s < 16; s++) {
            UU u0, u1;
            u0.i = *(const int4*)(pa0 + s * 64);
            u1.i = *(const int4*)(pa1 + s * 64);
            a00 = __builtin_amdgcn_mfma_f32_16x16x32_bf16(u0.v, br[0][s], a00, 0, 0, 0);
            a01 = __builtin_amdgcn_mfma_f32_16x16x32_bf16(u0.v, br[1][s], a01, 0, 0, 0);
            a10 = __builtin_amdgcn_mfma_f32_16x16x32_bf16(u1.v, br[0][s], a10, 0, 0, 0);
            a11 = __builtin_amdgcn_mfma_f32_16x16x32_bf16(u1.v, br[1][s], a11, 0, 0, 0);
        }
        // ---- partial write: Lp[kh][row][col], row = rh*32+m*16+q*4+r, col = n*16+cl
        {
            const int rbase = kh * 64 + rh * 32 + q * 4;
#pragma unroll
            for (int r = 0; r < 4; r++) {
                Lp[(rbase + r) * 36 + cl]           = a00[r];
                Lp[(rbase + r) * 36 + 16 + cl]      = a01[r];
                Lp[(rbase + 16 + r) * 36 + cl]      = a10[r];
                Lp[(rbase + 16 + r) * 36 + 16 + cl] = a11[r];
            }
        }
        __syncthreads();
        // ---- reduce k-halves + add xz + bias
        f32x4 v0, v1;
        {
            f32x4 za = *(const f32x4*)&Lp[r0 * 36 + quad * 4];
            f32x4 zb = *(const f32x4*)&Lp[(64 + r0) * 36 + quad * 4];
            f32x4 zc = *(const f32x4*)&Lp[(r0 + 32) * 36 + quad * 4];
            f32x4 zd = *(const f32x4*)&Lp[(64 + r0 + 32) * 36 + quad * 4];
            v0 = za + zb + px0 + bv;
            v1 = zc + zd + px1 + bv;
        }
        // ---- gather all 4 gates at quads 0,1 via shuffles (partners share r0)
        f32x4 j0 = sx4(v0, 2), j1 = sx4(v1, 2);
        f32x4 f0 = sx4(v0, 4), f1 = sx4(v1, 4);
        f32x4 o0 = sx4(v0, 6), o1 = sx4(v1, 6);
        if (quad < 2) {
            unsigned long long hp0 = 0, hp1 = 0;
            f32x4 hv0, hv1;
#pragma unroll
            for (int c2 = 0; c2 < 4; c2++) {
                float cn0 = cst[0][c2] * sigmoidf_(f0[c2] + 1.0f)
                          + sigmoidf_(v0[c2]) * tanhf_(j0[c2]);
                float cn1 = cst[1][c2] * sigmoidf_(f1[c2] + 1.0f)
                          + sigmoidf_(v1[c2]) * tanhf_(j1[c2]);
                cst[0][c2] = cn0; cst[1][c2] = cn1;
                float h0 = tanhf_(cn0) * sigmoidf_(o0[c2]);
                float h1 = tanhf_(cn1) * sigmoidf_(o1[c2]);
                hv0[c2] = h0; hv1[c2] = h1;
                hp0 |= ((unsigned long long)f2bf(h0)) << (16 * c2);
                hp1 |= ((unsigned long long)f2bf(h1)) << (16 * c2);
            }
            char* nslot = (char*)hrot + (size_t)(tt + 1) * 131072;
            st64cc(nslot + (size_t)r0 * 2048 + (n0 + ch * 4) * 2, hp0);
            st64cc(nslot + (size_t)(r0 + 32) * 2048 + (n0 + ch * 4) * 2, hp1);
            *(f32x4*)(out + (size_t)(r0 * 128 + tt) * 1024 + n0 + ch * 4) = hv0;
            *(f32x4*)(out + (size_t)((r0 + 32) * 128 + tt) * 1024 + n0 + ch * 4) = hv1;
        }
        __syncthreads();   // vmcnt(0): h stores ACK'd at IF before signal
        if (t == 0) {
            __hip_atomic_fetch_add(&cnt[tt], 1, __ATOMIC_RELAXED, __HIP_MEMORY_SCOPE_AGENT);
        }
    }
}

// ---------------- launch ----------------
extern "C" void kernel_launch(void* const* d_in, const int* in_sizes, int n_in,
                              void* d_out, int out_size, void* d_ws, size_t ws_size,
                              hipStream_t stream) {
    const float* x = (const float*)d_in[0];
    const float* W = (const float*)d_in[1];
    const float* b = (const float*)d_in[2];
    float* out = (float*)d_out;
    char* ws = (char*)d_ws;

    // workspace layout (bytes):
    unsigned short* WXTH = (unsigned short*)(ws);                              // 8 MB
    unsigned short* WXTL = (unsigned short*)(ws + (size_t)8  * 1024 * 1024);   // 8 MB
    unsigned short* WHT  = (unsigned short*)(ws + (size_t)16 * 1024 * 1024);   // 8 MB
    float*          XZ   = (float*)         (ws + (size_t)24 * 1024 * 1024);   // 128 MB fp32
    int*            CNT  = (int*)           (ws + (size_t)152 * 1024 * 1024);  // 4 KB
    unsigned short* HROT = (unsigned short*)(ws + (size_t)152 * 1024 * 1024 + 4096); // 129*128KB

    // zero CNT (4 KB) + HROT slot 0 (128 KB) = 135168 B = 33792 words
    k_init<<<256, 256, 0, stream>>>((uint32_t*)CNT, 33792);
    dim3 gtw(64, 32);
    k_tw<<<gtw, 256, 0, stream>>>(W, WXTH, WXTL, WHT);
    dim3 gg(32, 64);   // x: N/128, y: M/128
    k_gemm1<<<gg, 256, 0, stream>>>(x, WXTH, WXTL, XZ);
    k_rnn<<<NB, 256, 0, stream>>>(XZ, WHT, b, HROT, CNT, out);
}

// Round 8
// 1283.770 us; speedup vs baseline: 1.2686x; 1.2686x over previous
//
#include <hip/hip_runtime.h>
#include <stdint.h>

// Problem: B=64, T=128, F=1024, H=1024. x:[64,128,1024] f32, W:[2048,4096] f32, b:[4096] f32.
// out:[64,128,1024] f32.
#define BATCH 64
#define TSEQ  128
#define FDIM  1024
#define HDIM  1024
#define GDIM  4096              // 4H
#define MROWS 8192              // BATCH*TSEQ
#define NB2   64                // persistent blocks in recurrent phase (R8: 64, was 128)

typedef short bf16x8 __attribute__((ext_vector_type(8)));   // 8 bf16 in 4 VGPRs
typedef float f32x4  __attribute__((ext_vector_type(4)));

__device__ __forceinline__ unsigned short f2bf(float f) {
    union { float f; uint32_t u; } v; v.f = f;
    uint32_t u = v.u;
    return (unsigned short)((u + 0x7FFFu + ((u >> 16) & 1u)) >> 16);  // RNE
}
__device__ __forceinline__ float bf2f(unsigned short h) {
    union { uint32_t u; float f; } v; v.u = ((uint32_t)h) << 16; return v.f;
}
__device__ __forceinline__ float sigmoidf_(float x) { return 1.f / (1.f + __expf(-x)); }
__device__ __forceinline__ float tanhf_(float x)    { return 2.f / (1.f + __expf(-2.f * x)) - 1.f; }

union SP { short s[8]; int4 v; };
union UU { int4 i; bf16x8 v; };

// L2-bypass 8B store (relaxed agent atomic -> lands at Infinity Cache, the coherent point).
__device__ __forceinline__ void st64cc(void* p, unsigned long long v) {
    __hip_atomic_store((unsigned long long*)p, v, __ATOMIC_RELAXED, __HIP_MEMORY_SCOPE_AGENT);
}

// ---------------- init: zero cnt + h slot 0 ----------------
__global__ void k_init(uint32_t* p, int nwords) {
    int i = blockIdx.x * blockDim.x + threadIdx.x;
    int s = gridDim.x * blockDim.x;
    for (; i < nwords; i += s) p[i] = 0;
}

// ---------------- W fp32 [2048][4096] -> WxT hi/lo bf16 [4096][1024], WhT bf16 [4096][1024] ----
__global__ void k_tw(const float* __restrict__ W,
                     unsigned short* __restrict__ wxth, unsigned short* __restrict__ wxtl,
                     unsigned short* __restrict__ wht) {
    __shared__ float tile[64 * 65];
    const int nb = blockIdx.x;      // 0..63  (n tiles)
    const int kb = blockIdx.y;      // 0..31  (k tiles over 2048)
    const int t  = threadIdx.x;
    const int col = t & 63, rg = t >> 6;
#pragma unroll
    for (int i = 0; i < 16; i++) {
        int row = rg * 16 + i;
        tile[row * 65 + col] = W[(size_t)(kb * 64 + row) * 4096 + nb * 64 + col];
    }
    __syncthreads();
    if (kb < 16) {
        const int kbase = kb * 64;
#pragma unroll
        for (int i = 0; i < 16; i++) {
            int rp = rg * 16 + i;                      // n index within tile
            float v = tile[col * 65 + rp];             // = W[kb*64+col][nb*64+rp]
            unsigned short h = f2bf(v);
            size_t idx = (size_t)(nb * 64 + rp) * 1024 + kbase + col;
            wxth[idx] = h;
            wxtl[idx] = f2bf(v - bf2f(h));
        }
    } else {
        const int kbase = (kb - 16) * 64;
#pragma unroll
        for (int i = 0; i < 16; i++) {
            int rp = rg * 16 + i;
            float v = tile[col * 65 + rp];
            wht[(size_t)(nb * 64 + rp) * 1024 + kbase + col] = f2bf(v);
        }
    }
}

// ---------------- GEMM1: xz_f32[8192][4096] = x[8192][1024] @ Wx, split-bf16 (3-MFMA) ---------
__global__ __launch_bounds__(256) void k_gemm1(const float* __restrict__ Xf,
                                               const unsigned short* __restrict__ WxTh,
                                               const unsigned short* __restrict__ WxTl,
                                               float* __restrict__ xz) {
    __shared__ short Ash[128 * 40];   // stride 40 elems (80B) -> 2-way banks (free)
    __shared__ short Asl[128 * 40];
    __shared__ short Bsh[128 * 40];
    __shared__ short Bsl[128 * 40];
    const int n0 = blockIdx.x * 128;
    const int m0 = blockIdx.y * 128;
    const int t = threadIdx.x;
    const int wave = t >> 6, lane = t & 63;
    const int wm = wave >> 1, wn = wave & 1;
    const int q = lane >> 4, cl = lane & 15;
    const int row_a = t >> 2;            // 0..63
    const int kc = (t & 3) * 8;          // 8-elem chunk within the 32-elem k-slab

    f32x4 acc[4][4];
#pragma unroll
    for (int i = 0; i < 4; i++)
#pragma unroll
        for (int j = 0; j < 4; j++) acc[i][j] = (f32x4){0.f, 0.f, 0.f, 0.f};

    for (int kb = 0; kb < 32; kb++) {
        const int k0 = kb * 32;
        float va0[8], va1[8];
        {
            const float* p0 = Xf + (size_t)(m0 + row_a) * 1024 + k0 + kc;
            const float* p1 = Xf + (size_t)(m0 + 64 + row_a) * 1024 + k0 + kc;
            *(float4*)(va0)     = *(const float4*)(p0);
            *(float4*)(va0 + 4) = *(const float4*)(p0 + 4);
            *(float4*)(va1)     = *(const float4*)(p1);
            *(float4*)(va1 + 4) = *(const float4*)(p1 + 4);
        }
        int4 bh0 = *(const int4*)(WxTh + (size_t)(n0 + row_a)      * 1024 + k0 + kc);
        int4 bh1 = *(const int4*)(WxTh + (size_t)(n0 + 64 + row_a) * 1024 + k0 + kc);
        int4 bl0 = *(const int4*)(WxTl + (size_t)(n0 + row_a)      * 1024 + k0 + kc);
        int4 bl1 = *(const int4*)(WxTl + (size_t)(n0 + 64 + row_a) * 1024 + k0 + kc);
        __syncthreads();
        {
            SP h0, l0, h1, l1;
#pragma unroll
            for (int i = 0; i < 8; i++) {
                unsigned short h = f2bf(va0[i]);
                h0.s[i] = (short)h; l0.s[i] = (short)f2bf(va0[i] - bf2f(h));
                unsigned short g = f2bf(va1[i]);
                h1.s[i] = (short)g; l1.s[i] = (short)f2bf(va1[i] - bf2f(g));
            }
            *(int4*)(Ash + row_a * 40 + kc)        = h0.v;
            *(int4*)(Asl + row_a * 40 + kc)        = l0.v;
            *(int4*)(Ash + (64 + row_a) * 40 + kc) = h1.v;
            *(int4*)(Asl + (64 + row_a) * 40 + kc) = l1.v;
        }
        *(int4*)(Bsh + row_a * 40 + kc)        = bh0;
        *(int4*)(Bsh + (64 + row_a) * 40 + kc) = bh1;
        *(int4*)(Bsl + row_a * 40 + kc)        = bl0;
        *(int4*)(Bsl + (64 + row_a) * 40 + kc) = bl1;
        __syncthreads();
        bf16x8 ah[4], al[4], bh[4], bl[4];
#pragma unroll
        for (int i = 0; i < 4; i++) {
            ah[i] = *(const bf16x8*)(Ash + (wm * 64 + i * 16 + cl) * 40 + q * 8);
            al[i] = *(const bf16x8*)(Asl + (wm * 64 + i * 16 + cl) * 40 + q * 8);
        }
#pragma unroll
        for (int j = 0; j < 4; j++) {
            bh[j] = *(const bf16x8*)(Bsh + (wn * 64 + j * 16 + cl) * 40 + q * 8);
            bl[j] = *(const bf16x8*)(Bsl + (wn * 64 + j * 16 + cl) * 40 + q * 8);
        }
#pragma unroll
        for (int i = 0; i < 4; i++)
#pragma unroll
            for (int j = 0; j < 4; j++) {
                acc[i][j] = __builtin_amdgcn_mfma_f32_16x16x32_bf16(ah[i], bh[j], acc[i][j], 0, 0, 0);
                acc[i][j] = __builtin_amdgcn_mfma_f32_16x16x32_bf16(al[i], bh[j], acc[i][j], 0, 0, 0);
                acc[i][j] = __builtin_amdgcn_mfma_f32_16x16x32_bf16(ah[i], bl[j], acc[i][j], 0, 0, 0);
            }
    }
    // epilogue: C/D layout col=lane&15, row=q*4+reg; write fp32
#pragma unroll
    for (int i = 0; i < 4; i++) {
#pragma unroll
        for (int j = 0; j < 4; j++) {
            int gm = m0 + wm * 64 + i * 16 + q * 4;
            int gn = n0 + wn * 64 + j * 16 + cl;
#pragma unroll
            for (int r = 0; r < 4; r++)
                xz[(size_t)(gm + r) * 4096 + gn] = acc[i][j][r];
        }
    }
}

// ---------------- persistent recurrent kernel (R8: 64 blocks x 16 cols) ----------------
// Block owns 16 h-cols -> 4 MFMA n-tiles = gates i/j/f/o exactly (vcol = g*16 + cc).
// Ws = 128 KB LDS (XOR-swizzled). Per wave per step: 16 batch rows x 4 gates x 32 ksteps
// = 128 MFMAs. Gate math: lane (q,cl) owns rows q*4+r, col cl for all gates — no shuffles,
// all 64 lanes active. h via rotating write-once buffer (8B IF stores, cached 16B loads).
// out[] stores issued AFTER the signal (off the pre-signal vmcnt(0) drain / critical path).
__global__ __launch_bounds__(256, 1) void k_rnn(const float* __restrict__ xz,
                                                const unsigned short* __restrict__ WhT,
                                                const float* __restrict__ bias,
                                                unsigned short* hrot,    // 129 x [64][1024] bf16
                                                int* cnt,                // TSEQ step counters
                                                float* __restrict__ out) {
    __shared__ short Ws[64 * 1024];     // 128 KB
    __shared__ short hs[64 * 16];       // packed bf16 h staging, 2 KB
    __shared__ float hv[64 * 16];       // fp32 h staging for out, 4 KB
    const int t = threadIdx.x;
    const int blk = blockIdx.x;
    // XCD-grouped columns: the 8 blocks with blk&7==x own cols [x*128, x*128+128)
    const int n0 = (((blk & 7) << 3) | (blk >> 3)) * 16;
    const int wave = t >> 6, lane = t & 63;
    const int q = lane >> 4, cl = lane & 15;
    const int m = wave * 16 + cl;       // A-fragment batch row
    const int sw = cl & 7;

    // preload Wh slice into LDS: vcol = g*16+cc (gate g cols) <- WhT row g*1024+n0+cc
    {
        const int vcol = t >> 2;            // 0..63
        const int part = t & 3;             // 0..3
        const int g = vcol >> 4, cc2 = vcol & 15, swl = vcol & 7;
        const unsigned short* src = WhT + (size_t)(g * 1024 + n0 + cc2) * 1024;
        short* dstrow = Ws + vcol * 1024;
#pragma unroll
        for (int i = 0; i < 32; i++) {
            int kch = part * 32 + i;        // 16B chunk id 0..127
            int4 v = *(const int4*)(src + kch * 8);
            *(int4*)(dstrow + ((kch ^ swl) * 8)) = v;
        }
    }
    // bias per lane: col cl, 4 gates
    float bg[4];
#pragma unroll
    for (int g = 0; g < 4; g++) bg[g] = bias[g * 1024 + n0 + cl];
    float c[4] = {0.f, 0.f, 0.f, 0.f};   // c-state: rows wave*16+q*4+r, col cl
    __syncthreads();

    for (int tt = 0; tt < TSEQ; tt++) {
        // xz prefetch: 16 scalars (4 rows x 4 gates), coalesced across cl lanes; before spin
        float px[4][4];
#pragma unroll
        for (int r = 0; r < 4; r++) {
            const int m2 = wave * 16 + q * 4 + r;
            const float* xp = xz + (size_t)(m2 * 128 + tt) * 4096 + n0 + cl;
#pragma unroll
            for (int g = 0; g < 4; g++) px[r][g] = xp[g * 1024];
        }
        if (tt > 0) {
            if (t == 0) {
                while (__hip_atomic_load(&cnt[tt - 1], __ATOMIC_RELAXED,
                                         __HIP_MEMORY_SCOPE_AGENT) < NB2) { }
            }
            __syncthreads();
        }
        // ---- MFMA: A = h slot tt (cached loads), B = Ws; acc[g] per gate
        f32x4 acc[4];
#pragma unroll
        for (int g = 0; g < 4; g++) acc[g] = (f32x4){0.f, 0.f, 0.f, 0.f};
        const char* arow = (const char*)hrot + (size_t)tt * 131072 + (size_t)m * 2048 + q * 16;
        UU a; a.i = *(const int4*)(arow);
#pragma unroll 4
        for (int kb = 0; kb < 32; kb++) {
            UU acur = a;
            if (kb < 31) a.i = *(const int4*)(arow + (kb + 1) * 64);
            const int ch = (kb * 4 + q) ^ sw;
#pragma unroll
            for (int g = 0; g < 4; g++) {
                bf16x8 bfr = *(const bf16x8*)(Ws + (g * 16 + cl) * 1024 + ch * 8);
                acc[g] = __builtin_amdgcn_mfma_f32_16x16x32_bf16(acur.v, bfr, acc[g], 0, 0, 0);
            }
        }
        // ---- gates: lane (q,cl): rows wave*16+q*4+r, col n0+cl
#pragma unroll
        for (int r = 0; r < 4; r++) {
            const int m2 = wave * 16 + q * 4 + r;
            float vi = acc[0][r] + px[r][0] + bg[0];
            float vj = acc[1][r] + px[r][1] + bg[1];
            float vf = acc[2][r] + px[r][2] + bg[2] + 1.0f;   // forget bias
            float vo = acc[3][r] + px[r][3] + bg[3];
            float cn = c[r] * sigmoidf_(vf) + sigmoidf_(vi) * tanhf_(vj);
            c[r] = cn;
            float h = tanhf_(cn) * sigmoidf_(vo);
            hs[m2 * 16 + cl] = (short)f2bf(h);
            hv[m2 * 16 + cl] = h;
        }
        __syncthreads();   // hs/hv visible
        // ---- h publish: 256 threads x one 8B IF store (row t>>2, cols (t&3)*4..+4)
        {
            const int row = t >> 2, chq = t & 3;
            unsigned long long hp = *(const unsigned long long*)(hs + row * 16 + chq * 4);
            st64cc((char*)hrot + (size_t)(tt + 1) * 131072 + (size_t)row * 2048 + (n0 + chq * 4) * 2, hp);
        }
        __syncthreads();   // per-wave vmcnt(0) before barrier: h stores ACK'd at IF
        if (t == 0) {
            __hip_atomic_fetch_add(&cnt[tt], 1, __ATOMIC_RELAXED, __HIP_MEMORY_SCOPE_AGENT);
        }
        // ---- out stores AFTER the signal (private; drained by next step's barrier)
        {
            const int row = t >> 2, chq = t & 3;
            f32x4 hvv = *(const f32x4*)(hv + row * 16 + chq * 4);
            *(f32x4*)(out + (size_t)(row * 128 + tt) * 1024 + n0 + chq * 4) = hvv;
        }
    }
}

// ---------------- launch ----------------
extern "C" void kernel_launch(void* const* d_in, const int* in_sizes, int n_in,
                              void* d_out, int out_size, void* d_ws, size_t ws_size,
                              hipStream_t stream) {
    const float* x = (const float*)d_in[0];
    const float* W = (const float*)d_in[1];
    const float* b = (const float*)d_in[2];
    float* out = (float*)d_out;
    char* ws = (char*)d_ws;

    // workspace layout (bytes):
    unsigned short* WXTH = (unsigned short*)(ws);                              // 8 MB
    unsigned short* WXTL = (unsigned short*)(ws + (size_t)8  * 1024 * 1024);   // 8 MB
    unsigned short* WHT  = (unsigned short*)(ws + (size_t)16 * 1024 * 1024);   // 8 MB
    float*          XZ   = (float*)         (ws + (size_t)24 * 1024 * 1024);   // 128 MB fp32
    int*            CNT  = (int*)           (ws + (size_t)152 * 1024 * 1024);  // 4 KB
    unsigned short* HROT = (unsigned short*)(ws + (size_t)152 * 1024 * 1024 + 4096); // 129*128KB

    // zero CNT (4 KB) + HROT slot 0 (128 KB) = 135168 B = 33792 words
    k_init<<<256, 256, 0, stream>>>((uint32_t*)CNT, 33792);
    dim3 gtw(64, 32);
    k_tw<<<gtw, 256, 0, stream>>>(W, WXTH, WXTL, WHT);
    dim3 gg(32, 64);   // x: N/128, y: M/128
    k_gemm1<<<gg, 256, 0, stream>>>(x, WXTH, WXTL, XZ);
    k_rnn<<<NB2, 256, 0, stream>>>(XZ, WHT, b, HROT, CNT, out);
}